// Round 5
// baseline (62.006 us; speedup 1.0000x reference)
//
#include <hip/hip_runtime.h>

#define H_    128
#define W_    128
#define C_    256
#define PLANE (H_*W_)
#define ND    9
#define NDISP 81
#define TILE  8
#define HALO  4
#define KC    32
#define NSTEP 8
#define NT    10     // band: key rows 2w .. 2w+9 per wave
#define KSTR  258    // floats per staged channel plane (256 px + 2 pad)
#define SROW  170    // floats per query in sS: 10 rows x 17

typedef __attribute__((ext_vector_type(8))) short short8;
typedef __attribute__((ext_vector_type(4))) float f32x4;

union SharedU {
    float kbuf[KC * KSTR];      // 33.0 KB  [ch][px] channel-major K tile
    float sS[2][16 * SROW];     // 21.8 KB  epilogue scratch (overlays kbuf)
};

__device__ __forceinline__ void gload_lds16(const float* g, float* l) {
    __builtin_amdgcn_global_load_lds(
        (const __attribute__((address_space(1))) void*)g,
        (__attribute__((address_space(3))) void*)l, 16, 0, 0);
}

__device__ __forceinline__ unsigned cvtpk(float lo, float hi) {
    unsigned r;
    asm("v_cvt_pk_bf16_f32 %0, %1, %2" : "=v"(r) : "v"(lo), "v"(hi));
    return r;
}

#define STAGE_Q(P, C0) do {                                                   \
    const unsigned long long qsb_ = (unsigned long long)(fB + (size_t)(C0) * PLANE); \
    _Pragma("unroll")                                                         \
    for (int j = 0; j < 8; ++j)                                               \
        asm volatile("global_load_dword %0, %1, %2"                           \
                     : "=v"(qf[P][j])                                         \
                     : "v"(vq + (unsigned)(j * PLANE * 4)), "s"(qsb_)         \
                     : "memory");                                             \
} while (0)

__global__ __launch_bounds__(256, 4) void corr_mfma(
    const float* __restrict__ first, const float* __restrict__ second,
    float* __restrict__ out)
{
    __shared__ SharedU sh;

    const int tid  = threadIdx.x;
    const int lane = tid & 63;
    const int wv   = tid >> 6;

    // XCD-aware swizzle: 128 consecutive tiles per XCD
    const int bid  = blockIdx.x;
    const int tile = (bid & 7) * 128 + (bid >> 3);
    const int b  = tile >> 8;
    const int by = (tile >> 4) & 15;
    const int bx = tile & 15;
    const int x0 = bx * TILE, y0 = by * TILE;

    const float* fB = first  + (size_t)b * C_ * PLANE;
    const float* sB = second + (size_t)b * C_ * PLANE;

    // ---- per-lane constants ----
    const int g   = lane >> 4;        // MFMA k-group
    const int kxq = lane & 15;        // B-frag key col / A-frag query idx

    // K staging: lane -> (key row lane>>2, col chunk 4*(lane&3)); clamped
    const int krow = lane >> 2;
    const int kxc  = (lane & 3) * 4;
    const int gy   = min(max(y0 - HALO + krow, 0), H_ - 1);
    const int gx   = min(max(x0 - HALO + kxc, 0), W_ - 4);
    const int vko  = gy * W_ + gx;    // per-lane float offset within a plane

    // Q direct-load: lane owns (query q = 16*wv + kxq, channels 8g..8g+7)
    const int q  = 16 * wv + kxq;
    const int qy = q >> 3, qx = q & 7;
    const unsigned vq = (unsigned)((g * 8 * PLANE + (y0 + qy) * W_ + (x0 + qx)) * 4);

    f32x4 acc[NT];
    #pragma unroll
    for (int i = 0; i < NT; ++i) acc[i] = (f32x4){0.f, 0.f, 0.f, 0.f};

    float qf[2][8];

    auto stageK = [&](int c0) {
        #pragma unroll
        for (int r = 0; r < 8; ++r) {
            const int chp = 8 * wv + r;   // channel plane this wave stages
            gload_lds16(sB + (size_t)(c0 + chp) * PLANE + vko,
                        &sh.kbuf[chp * KSTR]);
        }
    };

    // ---- prologue: stage step 0 ----
    stageK(0);
    STAGE_Q(0, 0);

    // B-fragment base: float index (8g)*KSTR + (2wv)*16 + kxq
    const float* bbase = &sh.kbuf[(8 * g) * KSTR + (2 * wv) * 16 + kxq];

    // ---- main loop: 8 K-steps, single-buffered, cross-block overlap ----
    #pragma unroll
    for (int s = 0; s < NSTEP; ++s) {
        const int p = s & 1;
        asm volatile("s_waitcnt vmcnt(0)" ::: "memory");   // K[s] DMA + Q[s] done
        __builtin_amdgcn_s_barrier();                      // kbuf visible to all
        __builtin_amdgcn_sched_barrier(0);

        unsigned a0, a1, a2, a3;
        if (p == 0) {
            a0 = cvtpk(qf[0][0], qf[0][1]); a1 = cvtpk(qf[0][2], qf[0][3]);
            a2 = cvtpk(qf[0][4], qf[0][5]); a3 = cvtpk(qf[0][6], qf[0][7]);
        } else {
            a0 = cvtpk(qf[1][0], qf[1][1]); a1 = cvtpk(qf[1][2], qf[1][3]);
            a2 = cvtpk(qf[1][4], qf[1][5]); a3 = cvtpk(qf[1][6], qf[1][7]);
        }
        union { unsigned u[4]; short8 v; } ua = {{a0, a1, a2, a3}};

        if (s < NSTEP - 1) {   // issue next Q loads; hidden under compute
            if (p == 0) { STAGE_Q(1, (s + 1) * KC); } else { STAGE_Q(0, (s + 1) * KC); }
        }

        __builtin_amdgcn_s_setprio(1);
        #pragma unroll
        for (int nt = 0; nt < NT; ++nt) {
            float bj[8];
            #pragma unroll
            for (int j = 0; j < 8; ++j)
                bj[j] = bbase[j * KSTR + nt * 16];
            unsigned b0 = cvtpk(bj[0], bj[1]);
            unsigned b1 = cvtpk(bj[2], bj[3]);
            unsigned b2 = cvtpk(bj[4], bj[5]);
            unsigned b3 = cvtpk(bj[6], bj[7]);
            union { unsigned u[4]; short8 v; } ub = {{b0, b1, b2, b3}};
            acc[nt] = __builtin_amdgcn_mfma_f32_16x16x32_bf16(ua.v, ub.v, acc[nt], 0, 0, 0);
        }
        __builtin_amdgcn_s_setprio(0);

        __builtin_amdgcn_sched_barrier(0);
        __builtin_amdgcn_s_barrier();      // all waves done reading kbuf
        if (s < NSTEP - 1) stageK((s + 1) * KC);   // refill (drained next step)
    }

    // ---- epilogue: 2 rounds x 2 waves dump band-S, all threads gather ----
    const float scale = 1.0f / (float)C_;
    #pragma unroll
    for (int round = 0; round < 2; ++round) {
        __syncthreads();
        if ((wv >> 1) == round) {
            float* dst = sh.sS[wv & 1];
            #pragma unroll
            for (int nt = 0; nt < NT; ++nt) {
                #pragma unroll
                for (int r = 0; r < 4; ++r) {
                    const int qi = (lane >> 4) * 4 + r;
                    dst[qi * SROW + nt * 17 + kxq] = acc[nt][r];
                }
            }
        }
        __syncthreads();
        for (int idx = tid; idx < 2 * 16 * NDISP; idx += 256) {
            const int d   = idx >> 5;
            const int qq  = idx & 31;
            const int pp2 = qq >> 4;
            const int qi  = qq & 15;
            const int dy = d / ND, dx = d % ND;
            const int wv2 = round * 2 + pp2;
            const int gqy = 2 * wv2 + (qi >> 3);
            const int gqx = qi & 7;
            const int lr  = (qi >> 3) + dy;
            const int col = gqx + dx;
            const int kyg = y0 + gqy - HALO + dy;
            const int kxg = x0 + gqx - HALO + dx;
            float v = 0.f;
            if ((unsigned)kyg < (unsigned)H_ && (unsigned)kxg < (unsigned)W_)
                v = sh.sS[pp2][qi * SROW + lr * 17 + col] * scale;
            out[((size_t)b * NDISP + d) * PLANE + (size_t)(y0 + gqy) * W_ + (x0 + gqx)] = v;
        }
    }
}

extern "C" void kernel_launch(void* const* d_in, const int* in_sizes, int n_in,
                              void* d_out, int out_size, void* d_ws, size_t ws_size,
                              hipStream_t stream) {
    const float* first  = (const float*)d_in[0];
    const float* second = (const float*)d_in[1];
    float* out = (float*)d_out;

    dim3 grid(1024);
    dim3 block(256);
    corr_mfma<<<grid, block, 0, stream>>>(first, second, out);
}